// Round 9
// baseline (498.555 us; speedup 1.0000x reference)
//
#include <hip/hip_runtime.h>

#define HW 262144   // 512*512
#define EPSF 1e-5f

typedef __attribute__((ext_vector_type(8))) short bf16x8;
typedef __attribute__((ext_vector_type(4))) float f32x4;

__device__ __forceinline__ unsigned short f2bf(float f) {
    unsigned u = __builtin_bit_cast(unsigned, f);
    return (unsigned short)((u + 0x7FFFu + ((u >> 16) & 1u)) >> 16);  // RNE
}

typedef __attribute__((address_space(3))) unsigned lds_u32_t;
typedef __attribute__((address_space(1))) const unsigned glb_u32_t;
__device__ __forceinline__ void dma16(const void* gsrc, void* ldst) {
    __builtin_amdgcn_global_load_lds((glb_u32_t*)gsrc, (lds_u32_t*)ldst, 16, 0, 0);
}

// ws layout (bytes):
//   w2ws @ 0        : [8ch][4cz][64co][296] ushort = 1,212,416
//   w1ws @ 1212416  : [256hc][72ci] ushort (BN1-folded) = 36,864
//   t1ws @ 1249280  : float[256]
//   s2ws @ 1250304  : float[256]
//   t2ws @ 1251328  : float[256]
//   wdws @ 1252352  : [256co][72ci] ushort = 36,864
//   mskw @ 1289216  : byte[512]
#define W2WS_OFF 0
#define W1WS_OFF 1212416
#define T1WS_OFF 1249280
#define S2WS_OFF 1250304
#define T2WS_OFF 1251328
#define WDWS_OFF 1252352
#define MSKWS_OFF 1289216

// ---------------------------------------------------------------------------
__global__ __launch_bounds__(512) void kmask(const int* __restrict__ indices,
                                             int nB, char* __restrict__ ws) {
    unsigned char* mb = (unsigned char*)(ws + MSKWS_OFF);
    const int t = threadIdx.x;
    if (t < 512) mb[t] = 0;
    __syncthreads();
    if (t < nB) {
        int bn = indices[t*3+0], gh = indices[t*3+1], gw = indices[t*3+2];
        if ((unsigned)bn < 2u && (unsigned)gh < 16u && (unsigned)gw < 16u)
            mb[bn*256 + gh*16 + gw] = 1;
    }
}

// ---------------------------------------------------------------------------
__global__ __launch_bounds__(256) void kprep(
    const float* __restrict__ w1, const float* __restrict__ b1,
    const float* __restrict__ g1, const float* __restrict__ be1,
    const float* __restrict__ m1, const float* __restrict__ v1,
    const float* __restrict__ w2, const float* __restrict__ b2,
    const float* __restrict__ g2, const float* __restrict__ be2,
    const float* __restrict__ m2, const float* __restrict__ v2,
    const float* __restrict__ wd,
    char* __restrict__ ws)
{
    unsigned short* w2ws = (unsigned short*)(ws + W2WS_OFF);
    unsigned short* w1ws = (unsigned short*)(ws + W1WS_OFF);
    unsigned short* wdws = (unsigned short*)(ws + WDWS_OFF);
    float* t1ws = (float*)(ws + T1WS_OFF);
    float* s2ws = (float*)(ws + S2WS_OFF);
    float* t2ws = (float*)(ws + T2WS_OFF);

    const int bid = blockIdx.x, t = threadIdx.x;
    if (bid < 2304) {                      // w2: 589,824 elements
        int e  = bid*256 + t;
        int hc = e & 31;
        int r1 = e >> 5;
        int tap = r1 % 9;
        int r2 = r1 / 9;                   // < 2048
        int co = r2 & 63;
        int q  = r2 >> 6;                  // < 32
        int cz = q & 3, ch = q >> 2;
        float v = w2[(size_t)(cz*64+co)*2304 + (size_t)(ch*32+hc)*9 + tap];
        w2ws[((ch*4+cz)*64+co)*296 + tap*32 + hc] = f2bf(v);
    } else if (bid < 2368) {               // w1 folded
        int e = (bid-2304)*256 + t;
        int hc = e >> 6, ci = e & 63;
        float s1 = g1[hc] * rsqrtf(v1[hc] + EPSF);
        w1ws[hc*72 + ci] = f2bf(w1[hc*64+ci] * s1);
    } else if (bid < 2432) {               // wd
        int e = (bid-2368)*256 + t;
        int co = e >> 6, ci = e & 63;
        wdws[co*72 + ci] = f2bf(wd[co*64 + ci]);
    } else {
        if (t < 256) {
            float s1 = g1[t] * rsqrtf(v1[t] + EPSF);
            t1ws[t] = (b1[t]-m1[t])*s1 + be1[t];
            float s2 = g2[t] * rsqrtf(v2[t] + EPSF);
            s2ws[t] = s2;
            t2ws[t] = (b2[t]-m2[t])*s2 + be2[t];
        }
    }
}

// ---------------------------------------------------------------------------
// k1_mfma: unchanged (verified)
// ---------------------------------------------------------------------------
__global__ __launch_bounds__(256, 2) void k1_mfma(
    const float* __restrict__ x,
    const float* __restrict__ bd, const char* __restrict__ ws,
    const int* __restrict__ bstride, const int* __restrict__ boff,
    float* __restrict__ y)
{
    extern __shared__ char smem[];
    unsigned short* xT  = (unsigned short*)smem;            // [256][72]
    unsigned short* wdS = (unsigned short*)(smem + 36864);  // [256][72]
    float*          bdS = (float*)(smem + 73728);           // [256]

    const int t = threadIdx.x, lane = t & 63, w = t >> 6;
    const int m = lane & 15, g = lane >> 4;
    const int bid = blockIdx.x;
    const int n   = bid >> 10;
    const int row = (bid >> 1) & 511;
    const int c0  = (bid & 1) * 256;

    #pragma unroll
    for (int i = 0; i < 9; ++i)
        dma16((const char*)ws + WDWS_OFF + (t + i*256)*16,
              (char*)wdS + (t + i*256)*16);
    if (t < 64) dma16((const char*)bd + t*16, (char*)bdS + t*16);

    const size_t xbase = (size_t)n*64*HW + (size_t)row*512 + c0;
    #pragma unroll 4
    for (int jc = 0; jc < 16; ++jc) {
        int ci = w + 4*jc;
        float4 xv = *(const float4*)&x[xbase + (size_t)ci*HW + lane*4];
        xT[(lane*4+0)*72 + ci] = f2bf(xv.x);
        xT[(lane*4+1)*72 + ci] = f2bf(xv.y);
        xT[(lane*4+2)*72 + ci] = f2bf(xv.z);
        xT[(lane*4+3)*72 + ci] = f2bf(xv.w);
    }

    const int stride = bstride[0], off = boff[0];
    const bool safe = (stride == 32) && (off == 0);
    unsigned long long mv = 0;
    if (safe) {
        const unsigned char* mb = (const unsigned char*)(ws + MSKWS_OFF);
        mv = *(const unsigned long long*)&mb[n*256 + (row>>5)*16 + (bid&1)*8];
    }

    __syncthreads();

    bf16x8 bF[2][4];
    #pragma unroll
    for (int pxf = 0; pxf < 4; ++pxf)
        #pragma unroll
        for (int kk = 0; kk < 2; ++kk)
            bF[kk][pxf] = *(const bf16x8*)&xT[(w*64 + pxf*16 + m)*72 + kk*32 + g*8];

    const size_t ybase = (size_t)(n*256)*HW + (size_t)row*512 + c0;
    #pragma unroll 1
    for (int cof = 0; cof < 16; ++cof) {
        bf16x8 a0 = *(const bf16x8*)&wdS[(cof*16+m)*72 +      g*8];
        bf16x8 a1w = *(const bf16x8*)&wdS[(cof*16+m)*72 + 32 + g*8];
        f32x4 ac[4];
        #pragma unroll
        for (int pxf = 0; pxf < 4; ++pxf) {
            ac[pxf] = (f32x4){0.f,0.f,0.f,0.f};
            ac[pxf] = __builtin_amdgcn_mfma_f32_16x16x32_bf16(a0,  bF[0][pxf], ac[pxf], 0, 0, 0);
            ac[pxf] = __builtin_amdgcn_mfma_f32_16x16x32_bf16(a1w, bF[1][pxf], ac[pxf], 0, 0, 0);
        }
        #pragma unroll
        for (int pxf = 0; pxf < 4; ++pxf) {
            const int pxg = w*4 + pxf;
            const bool skip = safe && (((mv >> ((pxg>>1)*8)) & 0xffull) != 0ull);
            if (!skip) {
                #pragma unroll
                for (int j = 0; j < 4; ++j) {
                    const int co = cof*16 + g*4 + j;
                    y[ybase + (size_t)co*HW + pxg*16 + m] = ac[pxf][j] + bdS[co];
                }
            }
        }
    }
}

// ---------------------------------------------------------------------------
// k2_fused, round 9: overlap + read-sharing restructure.
//  * conv1(ch+1) hoisted before bar1 -> overlaps czh0 DMA drain; h-write
//    deferred to after bar4.  Barriers 5 -> 4 per ch.
//  * conv2 loop dx-major with dy/pr B-frag sharing: 60 reads/czh (was 72).
//  * w1s prefetched one ch ahead (drained by bar3/bar4 before use).
// LDS unchanged: xT 50,688 | w1s 4,608 | hS 28,160 | w2S 75,776 | tables 3,072
// ---------------------------------------------------------------------------
#define DMA_CZH(CH, CZH)                                                      \
    {                                                                         \
        const char* s_ = (const char*)w2ws                                    \
                         + (size_t)(CH)*151552 + (size_t)(CZH)*75776;         \
        _Pragma("unroll")                                                     \
        for (int i_ = 0; i_ < 9; ++i_)                                        \
            dma16(s_ + t*16 + i_*8192, (char*)w2S + t*16 + i_*8192);          \
        if (t < 128) dma16(s_ + 73728 + t*16, (char*)w2S + 73728 + t*16);     \
    }

#define CONV1_TO_A1()                                                         \
    {                                                                         \
        _Pragma("unroll")                                                     \
        for (int i = 0; i < 3; ++i) {                                         \
            a1[i][0] = (f32x4){0.f,0.f,0.f,0.f};                              \
            a1[i][1] = (f32x4){0.f,0.f,0.f,0.f};                              \
            const int tile = w*3 + i;                                         \
            if (tile < 22) {                                                  \
                _Pragma("unroll")                                             \
                for (int kk = 0; kk < 2; ++kk) {                              \
                    bf16x8 bF1 = *(const bf16x8*)&xT[(tile*16+m)*72 + kk*32 + g*8]; \
                    _Pragma("unroll")                                         \
                    for (int hct = 0; hct < 2; ++hct) {                       \
                        bf16x8 aF1 = *(const bf16x8*)&w1s[(hct*16+m)*72 + kk*32 + g*8]; \
                        a1[i][hct] = __builtin_amdgcn_mfma_f32_16x16x32_bf16( \
                                         aF1, bF1, a1[i][hct], 0, 0, 0);      \
                    }                                                         \
                }                                                             \
            }                                                                 \
        }                                                                     \
    }

#define HWRITE(CHX)                                                           \
    {                                                                         \
        _Pragma("unroll")                                                     \
        for (int i = 0; i < 3; ++i) {                                         \
            const int tile = w*3 + i;                                         \
            if (tile < 22) {                                                  \
                int p = tile*16 + m;                                          \
                int r = p / 34, c = p - r*34;                                 \
                int br = pz*8 + r - 1;                                        \
                bool valid = (c >= 1) && (c <= 32) && ((unsigned)br < 32u);   \
                _Pragma("unroll")                                             \
                for (int hct = 0; hct < 2; ++hct) {                           \
                    unsigned short hv[4];                                     \
                    _Pragma("unroll")                                         \
                    for (int j = 0; j < 4; ++j) {                             \
                        float tv = t1S[(CHX)*32 + hct*16 + g*4 + j];          \
                        float hf = fmaxf(a1[i][hct][j] + tv, 0.f);            \
                        hv[j] = valid ? f2bf(hf) : (unsigned short)0;         \
                    }                                                         \
                    unsigned lo = (unsigned)hv[0] | ((unsigned)hv[1] << 16);  \
                    unsigned hi = (unsigned)hv[2] | ((unsigned)hv[3] << 16);  \
                    *(uint2*)&hS[p*40 + hct*16 + g*4] = make_uint2(lo, hi);   \
                }                                                             \
            }                                                                 \
        }                                                                     \
    }

#define CONV2_CZH(CZH)                                                        \
    {                                                                         \
        __builtin_amdgcn_s_setprio(1);                                        \
        _Pragma("unroll")                                                     \
        for (int dx = 0; dx < 3; ++dx) {                                      \
            bf16x8 aF[3][4];                                                  \
            _Pragma("unroll")                                                 \
            for (int dy = 0; dy < 3; ++dy)                                    \
                _Pragma("unroll")                                             \
                for (int cof = 0; cof < 4; ++cof)                             \
                    aF[dy][cof] = *(const bf16x8*)&w2S[(cog*64 + cof*16 + m)*296 \
                                                       + (dy*3+dx)*32 + g*8]; \
            _Pragma("unroll")                                                 \
            for (int chf = 0; chf < 2; ++chf) {                               \
                bf16x8 bFr[4];                                                \
                _Pragma("unroll")                                             \
                for (int ro = 0; ro < 4; ++ro)                                \
                    bFr[ro] = *(const bf16x8*)&hS[((ph*2+ro)*34 + chf*16 + m + dx)*40 + g*8]; \
                _Pragma("unroll")                                             \
                for (int dy = 0; dy < 3; ++dy)                                \
                    _Pragma("unroll")                                         \
                    for (int pr = 0; pr < 2; ++pr)                            \
                        _Pragma("unroll")                                     \
                        for (int cof = 0; cof < 4; ++cof)                     \
                            acc[CZH][cof][pr*2+chf] =                         \
                                __builtin_amdgcn_mfma_f32_16x16x32_bf16(      \
                                    aF[dy][cof], bFr[pr+dy],                  \
                                    acc[CZH][cof][pr*2+chf], 0, 0, 0);        \
            }                                                                 \
        }                                                                     \
        __builtin_amdgcn_s_setprio(0);                                        \
    }

__global__ __launch_bounds__(512, 2) void k2_fused(
    const float* __restrict__ x, const int* __restrict__ indices,
    const char* __restrict__ ws,
    const int* __restrict__ bstride, const int* __restrict__ boff,
    float* __restrict__ y)
{
    extern __shared__ char smem[];
    unsigned short* xT  = (unsigned short*)smem;             // [352][72]  50,688B
    unsigned short* w1s = (unsigned short*)(smem + 50688);   // [32][72]    4,608B
    unsigned short* hS  = (unsigned short*)(smem + 55296);   // [352][40]  28,160B
    unsigned short* w2S = (unsigned short*)(smem + 83456);   // [128][296] 75,776B
    float* t1S = (float*)(smem + 159232);
    float* s2S = (float*)(smem + 160256);
    float* t2S = (float*)(smem + 161280);                    // -> 162,304B

    const unsigned short* w2ws = (const unsigned short*)(ws + W2WS_OFF);
    const unsigned short* w1ws = (const unsigned short*)(ws + W1WS_OFF);

    const int t    = threadIdx.x;
    const int lane = t & 63;
    const int w    = t >> 6;
    const int m    = lane & 15;
    const int g    = lane >> 4;
    const int cog  = w >> 2;        // 0..1  co-group of 64 within the czh half
    const int ph   = w & 3;         // 0..3  row-pair (rows ph*2, ph*2+1)

    const int bid = blockIdx.x;
    const int blk = bid >> 2, pz = bid & 3;
    const int bn = indices[blk*3+0], gr = indices[blk*3+1], gc = indices[blk*3+2];
    const int stride = bstride[0], off = boff[0];
    const int row0 = gr*stride + off, col0 = gc*stride + off;

    // ---- prologue DMAs: tables + w1s(0) ----
    if (t < 192) {
        const float* src = (t < 64) ? (const float*)(ws + T1WS_OFF)
                         : (t < 128) ? (const float*)(ws + S2WS_OFF)
                                     : (const float*)(ws + T2WS_OFF);
        float* dst = (t < 64) ? t1S : (t < 128) ? s2S : t2S;
        dma16(src + (lane)*4, dst + (lane)*4);
    }
    if (t < 288) dma16((const char*)w1ws + t*16, (char*)w1s + t*16);

    {   // stage xT (transpose to [px][ci], bf16), once
        const int half = lane >> 5, cc = lane & 31;
        for (int pb = w*80; pb < w*80 + 80; pb += 2) {
            int pi = pb + half;
            int r = pi >> 6, ci = pi & 63;
            int br = pz*8 + r - 1;
            if ((unsigned)br < 32u) {
                float xv = x[(size_t)bn*64*HW + (size_t)ci*HW
                             + (size_t)(row0+br)*512 + (col0+cc)];
                xT[(r*34 + cc + 1)*72 + ci] = f2bf(xv);
            }
        }
    }

    f32x4 acc[2][4][4];
    #pragma unroll
    for (int a = 0; a < 2; ++a)
        #pragma unroll
        for (int b = 0; b < 4; ++b)
            #pragma unroll
            for (int c = 0; c < 4; ++c) acc[a][b][c] = (f32x4){0.f,0.f,0.f,0.f};

    f32x4 a1[3][2];

    __syncthreads();               // P1: tables+w1s(0) drained, xT visible
    CONV1_TO_A1();                 // h(0) partials (w1s slice 0)
    __syncthreads();               // P2: w1s readers done
    if (t < 288) dma16((const char*)w1ws + 4608 + t*16, (char*)w1s + t*16);  // w1s(1)
    HWRITE(0);
    __syncthreads();               // P3: w1s(1) drained; h(0) visible

    #pragma unroll 1
    for (int ch = 0; ch < 8; ++ch) {
        DMA_CZH(ch, 0);
        if (ch < 7) { CONV1_TO_A1(); }   // h(ch+1) partials; overlaps czh0 DMA
        __syncthreads();                 // bar1: czh0 drained
        CONV2_CZH(0);
        __syncthreads();                 // bar2: czh0 reads done
        DMA_CZH(ch, 1);
        if (ch < 6) {
            if (t < 288) dma16((const char*)w1ws + (ch+2)*4608 + t*16,
                               (char*)w1s + t*16);
        }
        __syncthreads();                 // bar3: czh1 + w1s drained
        CONV2_CZH(1);
        __syncthreads();                 // bar4: hS/w2S readers done
        if (ch < 7) { HWRITE(ch+1); }    // visible by next bar1
    }

    // ---- epilogue: BN2 + relu + scatter ----
    const size_t yblk = (size_t)bn*256*HW;
    const int rbase = row0 + pz*8 + ph*2;
    #pragma unroll
    for (int czh = 0; czh < 2; ++czh) {
        #pragma unroll
        for (int cof = 0; cof < 4; ++cof) {
            #pragma unroll
            for (int j = 0; j < 4; ++j) {
                const int co = czh*128 + cog*64 + cof*16 + g*4 + j;
                float s2 = s2S[co], t2 = t2S[co];
                #pragma unroll
                for (int pxf = 0; pxf < 4; ++pxf) {
                    const int rr = rbase + (pxf>>1);
                    const int cc2 = col0 + (pxf&1)*16 + m;
                    y[yblk + (size_t)co*HW + (size_t)rr*512 + cc2] =
                        fmaxf(fmaf(acc[czh][cof][pxf][j], s2, t2), 0.f);
                }
            }
        }
    }
}

// ---------------------------------------------------------------------------
extern "C" void kernel_launch(void* const* d_in, const int* in_sizes, int n_in,
                              void* d_out, int out_size, void* d_ws, size_t ws_size,
                              hipStream_t stream) {
    const float* x       = (const float*)d_in[0];
    const int*   indices = (const int*)  d_in[2];
    const float* w1  = (const float*)d_in[3];
    const float* b1  = (const float*)d_in[4];
    const float* g1  = (const float*)d_in[5];
    const float* be1 = (const float*)d_in[6];
    const float* m1  = (const float*)d_in[7];
    const float* v1  = (const float*)d_in[8];
    const float* w2  = (const float*)d_in[9];
    const float* b2  = (const float*)d_in[10];
    const float* g2  = (const float*)d_in[11];
    const float* be2 = (const float*)d_in[12];
    const float* m2  = (const float*)d_in[13];
    const float* v2  = (const float*)d_in[14];
    const float* wd  = (const float*)d_in[21];
    const float* bd  = (const float*)d_in[22];
    const int* bstride = (const int*)d_in[24];
    const int* boff    = (const int*)d_in[25];
    float* y = (float*)d_out;
    char* ws = (char*)d_ws;

    const int nB = in_sizes[2] / 3;   // 256 blocks

    hipLaunchKernelGGL(kmask, dim3(1), dim3(512), 0, stream, indices, nB, ws);
    hipLaunchKernelGGL(kprep, dim3(2433), dim3(256), 0, stream,
                       w1, b1, g1, be1, m1, v1, w2, b2, g2, be2, m2, v2, wd, ws);
    hipLaunchKernelGGL(k1_mfma, dim3(2048), dim3(256), 74752, stream,
                       x, bd, ws, bstride, boff, y);
    hipLaunchKernelGGL(k2_fused, dim3(nB * 4), dim3(512), 162304, stream,
                       x, indices, ws, bstride, boff, y);
}